// Round 9
// baseline (769.839 us; speedup 1.0000x reference)
//
#include <hip/hip_runtime.h>
#include <hip/hip_bf16.h>
#include <stdint.h>

typedef unsigned short u16;
typedef __attribute__((ext_vector_type(8))) short bf16x8;
typedef __attribute__((ext_vector_type(4))) float f32x4;

#define KD 4096   // in_features (K)
#define ND 4096   // out_features (N)
#define MD 8192   // rows of x
#define NKT 64    // K-tiles of BK=64

// ---- fp32 -> bf16 round-to-nearest-even ----
__device__ __forceinline__ u16 f2bf(float f) {
    uint32_t u = __float_as_uint(f);
    u += 0x7FFFu + ((u >> 16) & 1u);
    return (u16)(u >> 16);
}

// ---- async global->LDS 16B ----
__device__ __forceinline__ void gload_lds16(const u16* g, u16* l) {
    __builtin_amdgcn_global_load_lds(
        (const __attribute__((address_space(1))) void*)g,
        (__attribute__((address_space(3))) void*)l, 16, 0, 0);
}

// =====================================================================
// Kernel 1: build W_t (n-major): W_t[n][k] = cluster[index[k*1024 + n/4]][n&3]
// =====================================================================
__global__ __launch_bounds__(256) void build_wt(
    const int* __restrict__ index, const float4* __restrict__ cluster4,
    u16* __restrict__ wt) {
    __shared__ int idx_s[64][32];
    const int t  = threadIdx.x;
    const int k0 = blockIdx.x * 64;
    const int g0 = blockIdx.y * 32;
    #pragma unroll
    for (int r = 0; r < 8; ++r) {
        int k = (t >> 5) + r * 8;
        int g = t & 31;
        idx_s[k][g] = index[(size_t)(k0 + k) * 1024 + g0 + g];
    }
    __syncthreads();
    const int g_local = t >> 3;
    const int k_local = (t & 7) * 8;
    u16 pk[4][8];
    #pragma unroll
    for (int j = 0; j < 8; ++j) {
        int idx = idx_s[k_local + j][g_local];
        float4 v = cluster4[idx];
        pk[0][j] = f2bf(v.x);
        pk[1][j] = f2bf(v.y);
        pk[2][j] = f2bf(v.z);
        pk[3][j] = f2bf(v.w);
    }
    const size_t nbase = (size_t)g0 * 4 + g_local * 4;
    #pragma unroll
    for (int c = 0; c < 4; ++c) {
        *reinterpret_cast<uint4*>(wt + (nbase + c) * KD + k0 + k_local) =
            *reinterpret_cast<const uint4*>(pk[c]);
    }
}

// =====================================================================
// Kernel 2: 256x256x64 8-phase GEMM — round-7 schedule with the A-path
// fused fp32->bf16 (reg-staged: global fp32 load 2 phases early ->
// f2bf -> swizzled ds_write_b128). B-path unchanged (gload_lds +
// inverse-swizzled source).
//  BUGFIXES vs round 8: (1) grid swizzle constant 128->64 (512 blocks;
//  128 sent m0 out of bounds -> memory fault). (2) A load col is LINEAR
//  (t&7)*8; only the LDS WRITE position is XOR-swizzled (round 8 used
//  the swizzled col for both -> linear layout under swizzled reads).
// vmcnt queue audit (per wave, in-order; entry state [rY4, B0'g2]):
//  P1 WVM(2) drains rY4          -> AWRITE(rY,buf1.A1)
//  P2 +{B1'g2, rX4}  P3 +{rY4, B0g2}
//  P4 WVM(6) drains B0'g2,B1'g2,rX4 (=8 oldest, order-robust)
//     -> buf1 B fence + rX -> AWRITE(rX,buf0.A0); BAR = buf1 ready
//  P5 WVM(2) drains rY4 -> AWRITE(rY,buf0.A1); +rX4
//  P6 +B1g2  P7 +{rY4, B0'g2}
//  P8 WVM(6) drains B0g2,rX4,B1g2 -> buf0 B fence + rX
//     -> AWRITE(rX,buf1.A0); BAR = buf0 ready; state [rY4, B0'g2] ✓
// LDS RAW/WAR: every AWRITE/STAGEB overwrite is >=1 barrier after all
// readers' lgkm drains; every reader is >=1 barrier after the writer's
// drain (writes drain at writer's next-phase WAIT_LGKM).
// =====================================================================
__global__ __launch_bounds__(512, 2) void gemm256(
    const float* __restrict__ X,  // [MD][KD] fp32
    const u16* __restrict__ Bt,   // [ND][KD] bf16
    const float* __restrict__ bias,
    float* __restrict__ C) {
    __shared__ __align__(16) u16 lds[65536];   // 128 KiB

    const int t    = threadIdx.x;
    const int lane = t & 63;
    const int wave = t >> 6;
    const int wm   = wave >> 2;      // 0..1
    const int wn   = wave & 3;       // 0..3

    // T1: bijective XCD swizzle for 512 blocks (512 % 8 == 0)
    const int bid = blockIdx.x;
    const int swz = (bid & 7) * 64 + (bid >> 3);
    const int n0  = (swz & 15) * 256;
    const int m0  = (swz >> 4) * 256;

    // ---- B staging: linear LDS dest, inverse-swizzled global source ----
    const u16* srcB[2];
    #pragma unroll
    for (int i = 0; i < 2; ++i) {
        int p   = i * 8192 + t * 16;
        int row = p >> 7;
        int cb  = (p & 127) ^ ((row & 7) << 4);
        srcB[i] = Bt + (size_t)(n0 + row) * KD + (cb >> 1);
    }
    const size_t HS = (size_t)128 * KD;   // half-tile (h=1) row step

    // ---- A staging geometry: 8 rows/thread-group; LINEAR global col,
    //      XOR-swizzled LDS write col (elems; multiples of 8 -> 16B ok)
    const int arow = t >> 3;                       // 0..63
    const int acol = (t & 7) * 8;                  // linear elem col
    const int aswz = acol ^ ((arow & 7) * 8);      // swizzled elem col

    // fragment-read swizzled column offsets (u16 elems), per kstep
    const int frow = lane & 15;
    int ce2[2];
    #pragma unroll
    for (int s = 0; s < 2; ++s)
        ce2[s] = ((s * 64 + ((lane >> 4) * 16)) ^ ((lane & 7) << 4)) >> 1;

    f32x4 acc[8][4] = {};
    bf16x8 aS[2][4][2];   // [mh][f][kstep]
    bf16x8 bR[2][2];      // [g][kstep]
    float4 rX[4], rY[4];  // two A-stage register slots (16 VGPR each)

#define ALOAD(R, h, kt) do {                                               \
    _Pragma("unroll")                                                      \
    for (int i_ = 0; i_ < 2; ++i_) {                                       \
        const float* s_ = X + (size_t)(m0 + (h) * 128 + i_ * 64 + arow)    \
                          * KD + (kt) * 64 + acol;                         \
        R[2 * i_]     = *(const float4*)(s_);                              \
        R[2 * i_ + 1] = *(const float4*)(s_ + 4);                          \
    } } while (0)

#define AWRITE(R, b, h) do {                                               \
    _Pragma("unroll")                                                      \
    for (int i_ = 0; i_ < 2; ++i_) {                                       \
        u16 pk_[8];                                                        \
        const float* f_ = (const float*)&R[2 * i_];                        \
        _Pragma("unroll")                                                  \
        for (int j_ = 0; j_ < 8; ++j_) pk_[j_] = f2bf(f_[j_]);             \
        *(bf16x8*)((u16*)lds + (b) * 32768 + (h) * 8192 +                  \
                   (i_ * 64 + arow) * 64 + aswz) =                         \
            *(const bf16x8*)pk_;                                           \
    } } while (0)

#define STAGEB(b, h, kt) do {                                              \
    _Pragma("unroll")                                                      \
    for (int i_ = 0; i_ < 2; ++i_) {                                       \
        gload_lds16(srcB[i_] + (size_t)(h) * HS + (kt) * 64,               \
                    (u16*)lds + (b) * 32768 + 16384 + (h) * 8192 +         \
                    i_ * 4096 + t * 8);                                    \
    } } while (0)

#define READA(b, mh) do {                                                  \
    _Pragma("unroll") for (int f_ = 0; f_ < 4; ++f_)                       \
    _Pragma("unroll") for (int s_ = 0; s_ < 2; ++s_)                       \
        aS[mh][f_][s_] = *(const bf16x8*)((u16*)lds + (b) * 32768 +        \
            ((wm * 128 + (mh) * 64 + f_ * 16 + frow) * 64) + ce2[s_]);     \
    } while (0)

#define READB(b, nh) do {                                                  \
    _Pragma("unroll") for (int g_ = 0; g_ < 2; ++g_)                       \
    _Pragma("unroll") for (int s_ = 0; s_ < 2; ++s_)                       \
        bR[g_][s_] = *(const bf16x8*)((u16*)lds + (b) * 32768 + 16384 +    \
            ((wn * 64 + (nh) * 32 + g_ * 16 + frow) * 64) + ce2[s_]);      \
    } while (0)

#define MFMA16(mh, nh) do {                                                \
    _Pragma("unroll") for (int f_ = 0; f_ < 4; ++f_)                       \
    _Pragma("unroll") for (int g_ = 0; g_ < 2; ++g_)                       \
    _Pragma("unroll") for (int s_ = 0; s_ < 2; ++s_)                       \
        acc[(mh)*4+f_][(nh)*2+g_] = __builtin_amdgcn_mfma_f32_16x16x32_bf16( \
            aS[mh][f_][s_], bR[g_][s_], acc[(mh)*4+f_][(nh)*2+g_], 0,0,0); \
    } while (0)

#define BAR() __builtin_amdgcn_s_barrier()
#define WAIT_LGKM() do { asm volatile("s_waitcnt lgkmcnt(0)" ::: "memory"); \
                         __builtin_amdgcn_sched_barrier(0); } while (0)
#define WVM(N) asm volatile("s_waitcnt vmcnt(" #N ")" ::: "memory")
#define PRIO1() __builtin_amdgcn_s_setprio(1)
#define PRIO0() __builtin_amdgcn_s_setprio(0)

    // ---- prologue ----
    ALOAD(rX, 0, 0);      // buf0.A0 <- tile0 (fp32)
    ALOAD(rY, 1, 0);      // buf0.A1 <- tile0
    STAGEB(0, 0, 0);      // buf0.B0
    STAGEB(0, 1, 0);      // buf0.B1
    WVM(4);               // drain rX,rY (leaves B0g2+B1g2)
    AWRITE(rX, 0, 0);
    AWRITE(rY, 0, 1);
    ALOAD(rX, 0, 1);      // buf1.A0 <- tile1
    ALOAD(rY, 1, 1);      // buf1.A1 <- tile1
    STAGEB(1, 0, 1);      // buf1.B0
    WVM(6);               // drains B0g2,B1g2,rX4 -> leaves [rY4, B0'g2]
    AWRITE(rX, 1, 0);     // buf1.A0
    WAIT_LGKM();          // drain own ds_writes
    BAR();                // buf0 (A written + B landed) ready, all waves

    // ---- main loop: 2 K-tiles / iteration, 8 phases ----
    for (int I = 0; I < NKT / 2; ++I) {
        const int tb  = 2 * I + 1;
        const int tp2 = (2 * I + 2) & (NKT - 1);   // wraps harmlessly at end
        const int tp3 = (2 * I + 3) & (NKT - 1);

        // P1: q(0,0) buf0; write buf1.A1 (rY); pre-issue P2's A-frags
        READA(0, 0); READB(0, 0);
        BAR(); WAIT_LGKM();
        PRIO1(); MFMA16(0, 0); PRIO0();
        WVM(2);              // drain rY (leaves B0'g2)
        AWRITE(rY, 1, 1);
        READA(0, 1);
        BAR();
        // P2: q(1,0) buf0; B-stage buf1.B1 (tb); A-load buf0.A0 (tp2)
        STAGEB(1, 1, tb);
        ALOAD(rX, 0, tp2);
        BAR(); WAIT_LGKM();
        PRIO1(); MFMA16(1, 0); PRIO0();
        READB(0, 1);
        BAR();
        // P3: q(0,1) buf0; A-load buf0.A1 (tp2); B-stage buf0.B0 (tp2)
        ALOAD(rY, 1, tp2);
        STAGEB(0, 0, tp2);
        BAR(); WAIT_LGKM();
        PRIO1(); MFMA16(0, 1); PRIO0();
        BAR();
        // P4: q(1,1) buf0; WVM(6) = buf1-B fence + rX; write buf0.A0
        BAR(); WAIT_LGKM();
        PRIO1(); MFMA16(1, 1); PRIO0();
        WVM(6);              // drains B0'g2,B1'g2,rX4; leaves [rY4,B0g2]
        AWRITE(rX, 0, 0);
        BAR();               // buf1 fully ready for ALL waves
        // P5: q(0,0) buf1; write buf0.A1 (rY); A-load buf1.A0 (tp3)
        READA(1, 0); READB(1, 0);
        BAR(); WAIT_LGKM();
        PRIO1(); MFMA16(0, 0); PRIO0();
        WVM(2);              // drain rY (leaves B0g2)
        AWRITE(rY, 0, 1);
        ALOAD(rX, 0, tp3);
        READA(1, 1);
        BAR();
        // P6: q(1,0) buf1; B-stage buf0.B1 (tp2)
        STAGEB(0, 1, tp2);
        BAR(); WAIT_LGKM();
        PRIO1(); MFMA16(1, 0); PRIO0();
        READB(1, 1);
        BAR();
        // P7: q(0,1) buf1; A-load buf1.A1 (tp3); B-stage buf1.B0 (tp3)
        ALOAD(rY, 1, tp3);
        STAGEB(1, 0, tp3);
        BAR(); WAIT_LGKM();
        PRIO1(); MFMA16(0, 1); PRIO0();
        BAR();
        // P8: q(1,1) buf1; WVM(6) = buf0-B fence + rX; write buf1.A0
        BAR(); WAIT_LGKM();
        PRIO1(); MFMA16(1, 1); PRIO0();
        WVM(6);              // drains B0g2,rX4,B1g2; leaves [rY4,B0'g2]
        AWRITE(rX, 1, 0);
        BAR();               // buf0 (tp2) fully ready for ALL waves
    }

    // ---- epilogue: C = acc + bias (16x16 C/D map, m89-verified) ----
    const int crow = (lane >> 4) * 4;
    float bv[4];
    #pragma unroll
    for (int g = 0; g < 4; ++g)
        bv[g] = bias[n0 + wn * 64 + g * 16 + frow];
    #pragma unroll
    for (int f = 0; f < 8; ++f) {
        const int mrow = m0 + wm * 128 + f * 16 + crow;
        #pragma unroll
        for (int g = 0; g < 4; ++g) {
            float* cp = C + (size_t)mrow * ND + n0 + wn * 64 + g * 16 + frow;
            #pragma unroll
            for (int r = 0; r < 4; ++r)
                cp[(size_t)r * ND] = acc[f][g][r] + bv[g];
        }
    }
#undef ALOAD
#undef AWRITE
#undef STAGEB
#undef READA
#undef READB
#undef MFMA16
#undef BAR
#undef WAIT_LGKM
#undef WVM
}

// =====================================================================
// Fallback (workspace too small): fp32 inline gather
// =====================================================================
__global__ __launch_bounds__(256) void fallback_gemm(
    const float* __restrict__ x, const float4* __restrict__ cluster4,
    const int* __restrict__ index, const float* __restrict__ bias,
    float* __restrict__ out) {
    const int m = blockIdx.y;
    const int g = blockIdx.x * 256 + threadIdx.x;
    const float* xr = x + (size_t)m * KD;
    float a0 = 0.f, a1 = 0.f, a2 = 0.f, a3 = 0.f;
    for (int k = 0; k < KD; ++k) {
        float xv = xr[k];
        float4 cv = cluster4[index[(size_t)k * 1024 + g]];
        a0 += xv * cv.x; a1 += xv * cv.y; a2 += xv * cv.z; a3 += xv * cv.w;
    }
    size_t o = (size_t)m * ND + (size_t)g * 4;
    out[o + 0] = a0 + bias[g * 4 + 0];
    out[o + 1] = a1 + bias[g * 4 + 1];
    out[o + 2] = a2 + bias[g * 4 + 2];
    out[o + 3] = a3 + bias[g * 4 + 3];
}

extern "C" void kernel_launch(void* const* d_in, const int* in_sizes, int n_in,
                              void* d_out, int out_size, void* d_ws, size_t ws_size,
                              hipStream_t stream) {
    const float* x       = (const float*)d_in[0];
    const float* cluster = (const float*)d_in[1];
    const int*   index   = (const int*)d_in[2];
    const float* bias    = (const float*)d_in[3];
    float* out = (float*)d_out;

    const size_t WT_BYTES = (size_t)ND * KD * sizeof(u16);   // 32 MB

    if (ws_size >= WT_BYTES) {
        u16* wt = (u16*)d_ws;
        build_wt<<<dim3(KD / 64, ND / 128), 256, 0, stream>>>(
            index, (const float4*)cluster, wt);
        gemm256<<<dim3((MD / 256) * (ND / 256)), 512, 0, stream>>>(
            x, wt, bias, out);
    } else {
        fallback_gemm<<<dim3(1024 / 256, MD), 256, 0, stream>>>(
            x, (const float4*)cluster, index, bias, out);
    }
}

// Round 10
// 271.953 us; speedup vs baseline: 2.8308x; 2.8308x over previous
//
#include <hip/hip_runtime.h>
#include <hip/hip_bf16.h>
#include <stdint.h>

typedef unsigned short u16;
typedef __attribute__((ext_vector_type(8))) short bf16x8;
typedef __attribute__((ext_vector_type(4))) float f32x4;

#define KD 4096   // in_features (K)
#define ND 4096   // out_features (N)
#define MD 8192   // rows of x
#define NKT 64    // K-tiles of BK=64

// ---- fp32 -> bf16 round-to-nearest-even ----
__device__ __forceinline__ u16 f2bf(float f) {
    uint32_t u = __float_as_uint(f);
    u += 0x7FFFu + ((u >> 16) & 1u);
    return (u16)(u >> 16);
}

// ---- async global->LDS 16B ----
__device__ __forceinline__ void gload_lds16(const u16* g, u16* l) {
    __builtin_amdgcn_global_load_lds(
        (const __attribute__((address_space(1))) void*)g,
        (__attribute__((address_space(3))) void*)l, 16, 0, 0);
}

// =====================================================================
// Kernel 1 (merged prep): blocks [0,2048) build W_t, blocks [2048,18432)
// convert x fp32->bf16. Overlaps the latency-bound cluster gather with
// the BW-bound convert; saves one launch gap.
// =====================================================================
__global__ __launch_bounds__(256) void prep(
    const int* __restrict__ index, const float4* __restrict__ cluster4,
    u16* __restrict__ wt,
    const float4* __restrict__ x4, uint4* __restrict__ xb) {
    __shared__ int idx_s[64][32];
    const int bid = blockIdx.x;
    const int t   = threadIdx.x;
    if (bid < 2048) {
        // ---- build W_t: W_t[n][k] = cluster[index[k*1024 + n/4]][n&3] ----
        const int k0 = (bid & 63) * 64;
        const int g0 = (bid >> 6) * 32;
        #pragma unroll
        for (int r = 0; r < 8; ++r) {
            int k = (t >> 5) + r * 8;
            int g = t & 31;
            idx_s[k][g] = index[(size_t)(k0 + k) * 1024 + g0 + g];
        }
        __syncthreads();
        const int g_local = t >> 3;
        const int k_local = (t & 7) * 8;
        u16 pk[4][8];
        #pragma unroll
        for (int j = 0; j < 8; ++j) {
            int idx = idx_s[k_local + j][g_local];
            float4 v = cluster4[idx];
            pk[0][j] = f2bf(v.x);
            pk[1][j] = f2bf(v.y);
            pk[2][j] = f2bf(v.z);
            pk[3][j] = f2bf(v.w);
        }
        const size_t nbase = (size_t)g0 * 4 + g_local * 4;
        #pragma unroll
        for (int c = 0; c < 4; ++c) {
            *reinterpret_cast<uint4*>(wt + (nbase + c) * KD + k0 + k_local) =
                *reinterpret_cast<const uint4*>(pk[c]);
        }
    } else {
        // ---- cvt x: 8 fp32 -> 8 bf16 per thread ----
        int i = (bid - 2048) * 256 + t;
        float4 a = x4[2 * i];
        float4 b = x4[2 * i + 1];
        u16 r[8] = {f2bf(a.x), f2bf(a.y), f2bf(a.z), f2bf(a.w),
                    f2bf(b.x), f2bf(b.y), f2bf(b.z), f2bf(b.w)};
        xb[i] = *reinterpret_cast<const uint4*>(r);
    }
}

// =====================================================================
// Kernel 2: 256x256x64 8-phase GEMM, 16x16x32 MFMA — round-2 schedule
// + NEXT-PHASE READ PRE-ISSUE: each phase's fragment ds_reads issue at
// the END of the previous phase (after its MFMA cluster, before the
// exit barrier) for same-buffer transitions (P1->P2, P2->P3, P5->P6,
// P6->P7). The LDS pipe then overlaps the matrix-pipe drain, and the
// next phase's lgkmcnt(0) is a no-op. Buffer-switch reads (P5-start,
// P1-start) stay AFTER the WVM(4)+BAR fence (round-4 race lesson:
// vmcnt is per-wave; the barrier is the cross-wave landing guarantee).
//   8 waves (2Mx4N), wave owns 128x64; LDS 128 KiB double buffer;
//   counted vmcnt(4) at phases 4/8 only (AFTER the MFMA burst).
//   Swizzle: colbyte ^= (row&7)<<4 on gload source + ds_read addr.
// =====================================================================
__global__ __launch_bounds__(512, 2) void gemm256(
    const u16* __restrict__ A,    // [MD][KD] bf16
    const u16* __restrict__ Bt,   // [ND][KD] bf16
    const float* __restrict__ bias,
    float* __restrict__ C) {
    __shared__ __align__(16) u16 lds[65536];   // 128 KiB

    const int t    = threadIdx.x;
    const int lane = t & 63;
    const int wave = t >> 6;
    const int wm   = wave >> 2;      // 0..1
    const int wn   = wave & 3;       // 0..3

    // T1: bijective XCD swizzle (512 % 8 == 0)
    const int bid = blockIdx.x;
    const int swz = (bid & 7) * 64 + (bid >> 3);
    const int n0  = (swz & 15) * 256;
    const int m0  = (swz >> 4) * 256;

    // staging: physical p = i*8192 + t*16 bytes within a 16 KiB half-tile
    // region [128 rows][128 B]; source address inverse-swizzled.
    const u16* srcA[2]; const u16* srcB[2];
    #pragma unroll
    for (int i = 0; i < 2; ++i) {
        int p   = i * 8192 + t * 16;
        int row = p >> 7;
        int cb  = (p & 127) ^ ((row & 7) << 4);
        srcA[i] = A  + (size_t)(m0 + row) * KD + (cb >> 1);
        srcB[i] = Bt + (size_t)(n0 + row) * KD + (cb >> 1);
    }
    const size_t HS = (size_t)128 * KD;   // half-tile (h=1) row step

    // fragment-read swizzled column offsets (u16 elems), per kstep
    const int frow = lane & 15;
    int ce2[2];
    #pragma unroll
    for (int s = 0; s < 2; ++s)
        ce2[s] = ((s * 64 + ((lane >> 4) * 16)) ^ ((lane & 7) << 4)) >> 1;

    f32x4 acc[8][4] = {};
    bf16x8 aS[2][4][2];   // [mh][f][kstep]
    bf16x8 bR[2][2];      // [g][kstep] (one nh at a time)

#define STAGE(isB, b, h, kt) do {                                          \
    _Pragma("unroll")                                                      \
    for (int i_ = 0; i_ < 2; ++i_) {                                       \
        const u16* s_ = ((isB) ? srcB[i_] : srcA[i_])                      \
                        + (size_t)(h) * HS + (kt) * 64;                    \
        u16* d_ = (u16*)lds + (b) * 32768 + (isB) * 16384                  \
                  + (h) * 8192 + i_ * 4096 + t * 8;                        \
        gload_lds16(s_, d_);                                               \
    } } while (0)

#define READA(b, mh) do {                                                  \
    _Pragma("unroll") for (int f_ = 0; f_ < 4; ++f_)                       \
    _Pragma("unroll") for (int s_ = 0; s_ < 2; ++s_)                       \
        aS[mh][f_][s_] = *(const bf16x8*)((u16*)lds + (b) * 32768 +        \
            ((wm * 128 + (mh) * 64 + f_ * 16 + frow) * 64) + ce2[s_]);     \
    } while (0)

#define READB(b, nh) do {                                                  \
    _Pragma("unroll") for (int g_ = 0; g_ < 2; ++g_)                       \
    _Pragma("unroll") for (int s_ = 0; s_ < 2; ++s_)                       \
        bR[g_][s_] = *(const bf16x8*)((u16*)lds + (b) * 32768 + 16384 +    \
            ((wn * 64 + (nh) * 32 + g_ * 16 + frow) * 64) + ce2[s_]);      \
    } while (0)

#define MFMA16(mh, nh) do {                                                \
    _Pragma("unroll") for (int f_ = 0; f_ < 4; ++f_)                       \
    _Pragma("unroll") for (int g_ = 0; g_ < 2; ++g_)                       \
    _Pragma("unroll") for (int s_ = 0; s_ < 2; ++s_)                       \
        acc[(mh)*4+f_][(nh)*2+g_] = __builtin_amdgcn_mfma_f32_16x16x32_bf16( \
            aS[mh][f_][s_], bR[g_][s_], acc[(mh)*4+f_][(nh)*2+g_], 0,0,0); \
    } while (0)

#define BAR() __builtin_amdgcn_s_barrier()
#define WAIT_LGKM() do { asm volatile("s_waitcnt lgkmcnt(0)" ::: "memory"); \
                         __builtin_amdgcn_sched_barrier(0); } while (0)
#define HINT_LGKM8() asm volatile("s_waitcnt lgkmcnt(8)" ::: "memory")
#define WAIT_VM4() asm volatile("s_waitcnt vmcnt(4)" ::: "memory")
#define PRIO1() __builtin_amdgcn_s_setprio(1)
#define PRIO0() __builtin_amdgcn_s_setprio(0)

    // ---- prologue: tile0 (buf0) fully + tile1.B0 + tile1.A0 ----
    STAGE(0, 0, 0, 0);   // buf0.A0  <- tile0
    STAGE(0, 0, 1, 0);   // buf0.A1
    STAGE(1, 0, 0, 0);   // buf0.B0
    STAGE(1, 0, 1, 0);   // buf0.B1
    STAGE(1, 1, 0, 1);   // buf1.B0  <- tile1
    STAGE(0, 1, 0, 1);   // buf1.A0
    WAIT_VM4();          // own tile0 stripes landed; barrier = all waves
    BAR();

    // ---- main loop: 2 K-tiles / iteration, 8 phases ----
    // lgkm audit (DS in-order): P1 drains own 12; P2 drains P1-end's 8
    // (aS[1]); P3 drains P2-end's 4 (bR); P4 drains nothing; P5..P8
    // mirror. Pre-issued reads come AFTER the MFMA that last uses the
    // same registers (program order => WAR safe, no extra VGPRs).
    for (int I = 0; I < NKT / 2; ++I) {
        const int tb  = 2 * I + 1;
        const int tp2 = (2 * I + 2) & (NKT - 1);   // wraps harmlessly at end
        const int tp3 = (2 * I + 3) & (NKT - 1);

        // P1: q(0,0) buf0; stage buf1.A1 (tb); pre-issue P2's A-frags
        READA(0, 0); READB(0, 0); STAGE(0, 1, 1, tb);
        HINT_LGKM8();
        BAR(); WAIT_LGKM();
        PRIO1(); MFMA16(0, 0); PRIO0();
        READA(0, 1);
        BAR();
        // P2: q(1,0) buf0; stage buf1.B1 (tb); pre-issue P3's B-frags
        STAGE(1, 1, 1, tb);
        BAR(); WAIT_LGKM();
        PRIO1(); MFMA16(1, 0); PRIO0();
        READB(0, 1);
        BAR();
        // P3: q(0,1) buf0; stage buf0.B0 (tp2)
        STAGE(1, 0, 0, tp2);
        BAR(); WAIT_LGKM();
        PRIO1(); MFMA16(0, 1); PRIO0();
        BAR();
        // P4: q(1,1) buf0; stage buf0.A0 (tp2); vmcnt AFTER MFMA
        STAGE(0, 0, 0, tp2);
        BAR(); WAIT_LGKM();
        PRIO1(); MFMA16(1, 1); PRIO0();
        WAIT_VM4();      // buf1 (tb) landed; BAR => for ALL waves
        BAR();
        // P5: q(0,0) buf1; stage buf0.A1 (tp2); pre-issue P6's A-frags
        READA(1, 0); READB(1, 0); STAGE(0, 0, 1, tp2);
        HINT_LGKM8();
        BAR(); WAIT_LGKM();
        PRIO1(); MFMA16(0, 0); PRIO0();
        READA(1, 1);
        BAR();
        // P6: q(1,0) buf1; stage buf0.B1 (tp2); pre-issue P7's B-frags
        STAGE(1, 0, 1, tp2);
        BAR(); WAIT_LGKM();
        PRIO1(); MFMA16(1, 0); PRIO0();
        READB(1, 1);
        BAR();
        // P7: q(0,1) buf1; stage buf1.B0 (tp3)
        STAGE(1, 1, 0, tp3);
        BAR(); WAIT_LGKM();
        PRIO1(); MFMA16(0, 1); PRIO0();
        BAR();
        // P8: q(1,1) buf1; stage buf1.A0 (tp3); vmcnt AFTER MFMA
        STAGE(0, 1, 0, tp3);
        BAR(); WAIT_LGKM();
        PRIO1(); MFMA16(1, 1); PRIO0();
        WAIT_VM4();      // buf0 (tp2) landed; BAR => for ALL waves
        BAR();
    }

    // ---- epilogue: C = acc + bias (16x16 C/D map, m89-verified) ----
    const int crow = (lane >> 4) * 4;
    float bv[4];
    #pragma unroll
    for (int g = 0; g < 4; ++g)
        bv[g] = bias[n0 + wn * 64 + g * 16 + frow];
    #pragma unroll
    for (int f = 0; f < 8; ++f) {
        const int mrow = m0 + wm * 128 + f * 16 + crow;
        #pragma unroll
        for (int g = 0; g < 4; ++g) {
            float* cp = C + (size_t)mrow * ND + n0 + wn * 64 + g * 16 + frow;
            #pragma unroll
            for (int r = 0; r < 4; ++r)
                cp[(size_t)r * ND] = acc[f][g][r] + bv[g];
        }
    }
#undef STAGE
#undef READA
#undef READB
#undef MFMA16
#undef BAR
#undef WAIT_LGKM
#undef HINT_LGKM8
#undef WAIT_VM4
}

// =====================================================================
// Fallback (workspace too small): fp32 inline gather
// =====================================================================
__global__ __launch_bounds__(256) void fallback_gemm(
    const float* __restrict__ x, const float4* __restrict__ cluster4,
    const int* __restrict__ index, const float* __restrict__ bias,
    float* __restrict__ out) {
    const int m = blockIdx.y;
    const int g = blockIdx.x * 256 + threadIdx.x;
    const float* xr = x + (size_t)m * KD;
    float a0 = 0.f, a1 = 0.f, a2 = 0.f, a3 = 0.f;
    for (int k = 0; k < KD; ++k) {
        float xv = xr[k];
        float4 cv = cluster4[index[(size_t)k * 1024 + g]];
        a0 += xv * cv.x; a1 += xv * cv.y; a2 += xv * cv.z; a3 += xv * cv.w;
    }
    size_t o = (size_t)m * ND + (size_t)g * 4;
    out[o + 0] = a0 + bias[g * 4 + 0];
    out[o + 1] = a1 + bias[g * 4 + 1];
    out[o + 2] = a2 + bias[g * 4 + 2];
    out[o + 3] = a3 + bias[g * 4 + 3];
}

extern "C" void kernel_launch(void* const* d_in, const int* in_sizes, int n_in,
                              void* d_out, int out_size, void* d_ws, size_t ws_size,
                              hipStream_t stream) {
    const float* x       = (const float*)d_in[0];
    const float* cluster = (const float*)d_in[1];
    const int*   index   = (const int*)d_in[2];
    const float* bias    = (const float*)d_in[3];
    float* out = (float*)d_out;

    const size_t WT_BYTES = (size_t)ND * KD * sizeof(u16);
    const size_t XB_BYTES = (size_t)MD * KD * sizeof(u16);

    if (ws_size >= WT_BYTES + XB_BYTES) {
        u16* wt = (u16*)d_ws;
        u16* xb = (u16*)((char*)d_ws + WT_BYTES);
        prep<<<2048 + (MD * KD / 8) / 256, 256, 0, stream>>>(
            index, (const float4*)cluster, wt, (const float4*)x, (uint4*)xb);
        gemm256<<<dim3((MD / 256) * (ND / 256)), 512, 0, stream>>>(
            xb, wt, bias, out);
    } else {
        fallback_gemm<<<dim3(1024 / 256, MD), 256, 0, stream>>>(
            x, (const float4*)cluster, index, bias, out);
    }
}